// Round 7
// baseline (1007.914 us; speedup 1.0000x reference)
//
#include <hip/hip_runtime.h>
#include <math.h>

#define KD     768     // embedding dim (elements = bytes in fp8)
#define MT     128     // M tile (queries) per block
#define NT     128     // N tile (bank rows) per chunk
#define KB     128     // K bytes per chunk (one mfma_scale K=128)
#define NKC    6       // K chunks (768/128)
#define NSP    4       // bank splits
#define BIGF   3.0e38f

typedef __attribute__((ext_vector_type(4))) int   i32x4;
typedef __attribute__((ext_vector_type(8))) int   i32x8;
typedef __attribute__((ext_vector_type(4))) float f32x4;

// ---- software RNE float -> OCP e4m3fn (data ~N(0,1); saturation irrelevant)
__device__ __forceinline__ unsigned f2e4m3(float x) {
    unsigned u = __float_as_uint(x);
    unsigned s = (u >> 24) & 0x80u;
    float ax = __uint_as_float(u & 0x7fffffffu);
    if (ax < 0.015625f) {                       // subnormal region: step 2^-9
        int n = (int)rintf(ax * 512.0f);        // RNE, n in [0,8]
        if (n >= 8) return s | 0x08u;
        return s | (unsigned)n;
    }
    if (ax >= 464.0f) return s | 0x7Eu;         // saturate to 448
    unsigned m = __float_as_uint(ax);
    unsigned low = m & 0xFFFFFu;
    unsigned r = m >> 20;
    r += (low > 0x80000u) || (low == 0x80000u && (r & 1u));
    int ef = (int)(r >> 3) - 120;               // -127 + 7 (carry-safe)
    return s | ((unsigned)ef << 3) | (r & 7u);
}

__device__ __forceinline__ void ins3(float* t, float v) {
    float lo0 = fminf(t[0], v);
    float hi0 = fmaxf(t[0], v);
    float lo1 = fminf(t[1], hi0);
    float hi1 = fmaxf(t[1], hi0);
    float lo2 = fminf(t[2], hi1);
    t[0] = lo0; t[1] = lo1; t[2] = lo2;
}
__device__ __forceinline__ void async16(unsigned char* lds, const unsigned char* g) {
    __builtin_amdgcn_global_load_lds(
        (const __attribute__((address_space(1))) unsigned int*)g,
        (__attribute__((address_space(3))) unsigned int*)lds, 16, 0, 0);
}

// ---- emb [B][768][1024] -> qf8 [B*1024][768] e4m3 + exact fp32 q2 (fused) ----
__global__ void q_prep_k(const float* __restrict__ emb, unsigned char* __restrict__ qf8,
                         float* __restrict__ q2) {
    __shared__ float s[64][65];
    int b   = blockIdx.x >> 4;
    int hw0 = (blockIdx.x & 15) * 64;
    const float* src = emb + (size_t)b * KD * 1024;
    unsigned int* q4 = (unsigned int*)qf8;
    float part[4] = {0.f, 0.f, 0.f, 0.f};
    for (int e0 = 0; e0 < KD; e0 += 64) {
        __syncthreads();
        #pragma unroll
        for (int i = 0; i < 16; ++i) {
            int idx = threadIdx.x + i * 256;      // 0..4095
            int ee = idx >> 6, hh = idx & 63;
            s[ee][hh] = src[(size_t)(e0 + ee) * 1024 + hw0 + hh];
        }
        __syncthreads();
        #pragma unroll
        for (int i = 0; i < 4; ++i) {
            int slot = threadIdx.x + i * 256;     // 0..1023 : (qq, e4)
            int qq = slot >> 4, e4 = slot & 15;
            float v0 = s[e4 * 4 + 0][qq], v1 = s[e4 * 4 + 1][qq];
            float v2 = s[e4 * 4 + 2][qq], v3 = s[e4 * 4 + 3][qq];
            unsigned p = f2e4m3(v0) | (f2e4m3(v1) << 8)
                       | (f2e4m3(v2) << 16) | (f2e4m3(v3) << 24);
            q4[((size_t)b * 1024 + hw0 + qq) * (KD / 4) + e0 / 4 + e4] = p;
            part[i] = fmaf(v0, v0, part[i]); part[i] = fmaf(v1, v1, part[i]);
            part[i] = fmaf(v2, v2, part[i]); part[i] = fmaf(v3, v3, part[i]);
        }
    }
    #pragma unroll
    for (int i = 0; i < 4; ++i) {                 // 16 consecutive lanes share qq
        float p = part[i];
        #pragma unroll
        for (int off = 1; off < 16; off <<= 1) p += __shfl_xor(p, off, 64);
        if ((threadIdx.x & 15) == 0) {
            int qq = (threadIdx.x + i * 256) >> 4;
            q2[b * 1024 + hw0 + qq] = p;
        }
    }
}

// ---- bank -> bf8 e4m3 (zero-padded) + exact fp32 b2 norms (BIGF pad) ----
__global__ void bank_prep_k(const float* __restrict__ bank, unsigned char* __restrict__ bf8,
                            float* __restrict__ b2, int N, int Npad) {
    int gid = blockIdx.x * 256 + threadIdx.x;
    int row = gid >> 6, lane = gid & 63;
    if (row >= Npad) return;
    unsigned int* b4 = (unsigned int*)bf8;
    if (row < N) {
        const float4* src = (const float4*)(bank + (size_t)row * KD);
        float s = 0.f;
        #pragma unroll
        for (int i = 0; i < KD / 256; ++i) {
            float4 v = src[lane + i * 64];
            s = fmaf(v.x, v.x, s); s = fmaf(v.y, v.y, s);
            s = fmaf(v.z, v.z, s); s = fmaf(v.w, v.w, s);
            unsigned p = f2e4m3(v.x) | (f2e4m3(v.y) << 8)
                       | (f2e4m3(v.z) << 16) | (f2e4m3(v.w) << 24);
            b4[(size_t)row * (KD / 4) + lane + i * 64] = p;
        }
        #pragma unroll
        for (int off = 32; off; off >>= 1) s += __shfl_down(s, off, 64);
        if (lane == 0) b2[row] = s;
    } else {
        #pragma unroll
        for (int i = 0; i < KD / 256; ++i) b4[(size_t)row * (KD / 4) + lane + i * 64] = 0;
        if (lane == 0) b2[row] = BIGF;
    }
}

// ---- stage one 16 KB B chunk (128 rows x 128 B), XOR-swizzled ----
__device__ __forceinline__ void stage_b(unsigned char* dst, const unsigned char* gB,
                                        int kc, int tid) {
    #pragma unroll
    for (int i = 0; i < 2; ++i) {
        int s = tid + i * 512;
        int m = s >> 3, g = s & 7;
        int G = g ^ (m & 7);
        async16(&dst[s * 16], gB + (size_t)m * KD + kc * KB + G * 16);
    }
}

__device__ __forceinline__ i32x8 frag_read(const unsigned char* st, int base, int o0, int o1) {
    i32x4 lo = *(const i32x4*)&st[base + o0];
    i32x4 hi = *(const i32x4*)&st[base + o1];
    return __builtin_shufflevector(lo, hi, 0, 1, 2, 3, 4, 5, 6, 7);
}

// ---- main: persistent-A fp8 MFMA distance GEMM, double-buffered B ----
// grid = 256 (1 block/CU, 512 thr). bx%8 = XCD; per XCD: 16 mts x 2 sps ->
// A resident 16x96 KB = 1.5 MB/L2, 16 lockstep same-sp blocks share B stream.
// A tile (96 KB) lives in LDS for the whole block; only B chunks stream.
__global__ __launch_bounds__(512, 2)
void knn_mfma_k(const unsigned char* __restrict__ qf8, const unsigned char* __restrict__ bf8,
                const float* __restrict__ b2g, float* __restrict__ cand,
                int ntiles, int Q) {
    __shared__ unsigned char Ast[MT * KD];        // 98304 B, rows of 48 16B-groups
    __shared__ unsigned char Bst[2][NT * KB];     // 2 x 16384 B

    const int tid  = threadIdx.x;
    const int lane = tid & 63;
    const int quad = lane >> 4;
    const int l15  = lane & 15;
    const int wid  = tid >> 6;                    // 0..7
    const int wm   = wid & 1;                     // M half (64)
    const int wn   = wid >> 1;                    // N quarter (32)
    const int xr   = l15 & 7;

    const int bx   = blockIdx.x;
    const int xcd  = bx & 7;
    const int j    = bx >> 3;                     // 0..31
    const int sp   = (j >> 4) + 2 * (xcd >> 2);   // 0..3
    const int mt   = (xcd & 3) * 16 + (j & 15);   // 0..63
    const int Mbase = mt * MT;

    // ---- stage full A tile once (6144 slots of 16 B, XOR swizzle per row) ----
    const unsigned char* gA = qf8 + (size_t)Mbase * KD;
    #pragma unroll
    for (int i = 0; i < 12; ++i) {
        int s = tid + i * 512;
        int m = s / 48, g = s % 48;
        int G = g ^ (m & 7);
        async16(&Ast[s * 16], gA + (size_t)m * KD + G * 16);
    }

    const unsigned char* gB = bf8 + (size_t)sp * NT * KD;
    stage_b(Bst[0], gB, 0, tid);

    float top3[48];
    #pragma unroll
    for (int i = 0; i < 48; ++i) top3[i] = BIGF;

    f32x4 acc[4][2];
    #pragma unroll
    for (int a = 0; a < 4; ++a) {
        acc[a][0] = (f32x4){0.f, 0.f, 0.f, 0.f};
        acc[a][1] = (f32x4){0.f, 0.f, 0.f, 0.f};
    }
    float b2v0 = b2g[sp * NT + 32 * wn + l15];
    float b2v1 = b2g[sp * NT + 32 * wn + 16 + l15];

    __syncthreads();                              // A + B[0] resident

    int cur = 0;
    for (int nt = sp; nt < ntiles; nt += NSP) {
        const bool lastTile = (nt + NSP >= ntiles);
        const unsigned char* gBn = bf8 + (size_t)(nt + NSP) * NT * KD;

        #pragma unroll
        for (int kc = 0; kc < NKC; ++kc) {
            // stage next chunk into the other buffer (issued before MFMA work)
            if (kc < NKC - 1)      stage_b(Bst[cur ^ 1], gB,  kc + 1, tid);
            else if (!lastTile)    stage_b(Bst[cur ^ 1], gBn, 0,      tid);

            // MFMA on current chunk: A from persistent LDS, B from buf[cur]
            const int o0 = ((2 * quad) ^ xr) * 16;
            const int o1 = ((2 * quad + 1) ^ xr) * 16;
            i32x8 bfr[2];
            #pragma unroll
            for (int ni = 0; ni < 2; ++ni) {
                int n = 32 * wn + 16 * ni + l15;
                bfr[ni] = frag_read(Bst[cur], n * KB, o0, o1);
            }
            #pragma unroll
            for (int mi = 0; mi < 4; ++mi) {
                int m = 64 * wm + 16 * mi + l15;
                i32x8 af = frag_read(Ast, m * KD + kc * KB, o0, o1);
                #pragma unroll
                for (int ni = 0; ni < 2; ++ni)
                    acc[mi][ni] = __builtin_amdgcn_mfma_scale_f32_16x16x128_f8f6f4(
                        af, bfr[ni], acc[mi][ni], 0, 0,   // fp8 x fp8
                        0, 127, 0, 127);                  // identity E8M0 scales
            }
            __syncthreads();
            cur ^= 1;
        }

        // epilogue: s = b2 - 2*dot (q2 added in scores_k; order-preserving)
        #pragma unroll
        for (int mi = 0; mi < 4; ++mi)
            #pragma unroll
            for (int r = 0; r < 4; ++r) {
                float s0 = fmaf(-2.f, acc[mi][0][r], b2v0);
                float s1 = fmaf(-2.f, acc[mi][1][r], b2v1);
                ins3(&top3[(mi * 4 + r) * 3], s0);
                ins3(&top3[(mi * 4 + r) * 3], s1);
            }
        #pragma unroll
        for (int a = 0; a < 4; ++a) {
            acc[a][0] = (f32x4){0.f, 0.f, 0.f, 0.f};
            acc[a][1] = (f32x4){0.f, 0.f, 0.f, 0.f};
        }
        if (!lastTile) {
            b2v0 = b2g[(nt + NSP) * NT + 32 * wn + l15];
            b2v1 = b2g[(nt + NSP) * NT + 32 * wn + 16 + l15];
        }
        gB = gBn;
    }

    // merge the 16 column-partials per query row via shfl_xor butterfly
    #pragma unroll
    for (int mi = 0; mi < 4; ++mi)
        #pragma unroll
        for (int r = 0; r < 4; ++r) {
            float a0 = top3[(mi * 4 + r) * 3 + 0];
            float a1 = top3[(mi * 4 + r) * 3 + 1];
            float a2 = top3[(mi * 4 + r) * 3 + 2];
            #pragma unroll
            for (int off = 1; off < 16; off <<= 1) {
                float b0 = __shfl_xor(a0, off, 64);
                float b1 = __shfl_xor(a1, off, 64);
                float b2x = __shfl_xor(a2, off, 64);
                float t[3] = {a0, a1, a2};
                ins3(t, b0); ins3(t, b1); ins3(t, b2x);
                a0 = t[0]; a1 = t[1]; a2 = t[2];
            }
            if (l15 == 0) {
                int row = Mbase + 64 * wm + 16 * mi + 4 * quad + r;
                float* o = cand + ((size_t)(sp * 4 + wn) * Q + row) * 3;
                o[0] = a0; o[1] = a1; o[2] = a2;
            }
        }
}

// ---- merge 16 split-partials (s = b2-2dot) -> d2 = q2+s -> mean sqrt ----
__global__ void scores_k(const float* __restrict__ cand, const float* __restrict__ q2g,
                         float* __restrict__ scores, int Q) {
    int idx = blockIdx.x * blockDim.x + threadIdx.x;
    if (idx >= Q) return;
    float best[3] = {BIGF, BIGF, BIGF};
    for (int sp = 0; sp < 16; sp++) {
        const float* c = cand + ((size_t)sp * Q + idx) * 3;
        ins3(best, c[0]); ins3(best, c[1]); ins3(best, c[2]);
    }
    float q2 = q2g[idx];
    float s = (sqrtf(fmaxf(q2 + best[0], 1e-12f)) +
               sqrtf(fmaxf(q2 + best[1], 1e-12f)) +
               sqrtf(fmaxf(q2 + best[2], 1e-12f))) * (1.f / 3.f);
    scores[idx] = s;
}

// ---- bilinear x16 upsample, half-pixel, edge clamp ----
__global__ void upsample_k(const float* __restrict__ scores, float* __restrict__ out, int total) {
    int idx = blockIdx.x * blockDim.x + threadIdx.x;
    if (idx >= total) return;
    int x = idx & 511;
    int y = (idx >> 9) & 511;
    int b = idx >> 18;
    float sx = (x + 0.5f) * (1.f / 16.f) - 0.5f;
    float sy = (y + 0.5f) * (1.f / 16.f) - 0.5f;
    int x0 = (int)floorf(sx);
    int y0 = (int)floorf(sy);
    float wx = sx - (float)x0;
    float wy = sy - (float)y0;
    int x0c = min(max(x0, 0), 31), x1c = min(max(x0 + 1, 0), 31);
    int y0c = min(max(y0, 0), 31), y1c = min(max(y0 + 1, 0), 31);
    const float* sb = scores + (size_t)b * 1024;
    float v00 = sb[y0c * 32 + x0c], v01 = sb[y0c * 32 + x1c];
    float v10 = sb[y1c * 32 + x0c], v11 = sb[y1c * 32 + x1c];
    float v0 = v00 + wx * (v01 - v00);
    float v1 = v10 + wx * (v11 - v10);
    out[idx] = v0 + wy * (v1 - v0);
}

extern "C" void kernel_launch(void* const* d_in, const int* in_sizes, int n_in,
                              void* d_out, int out_size, void* d_ws, size_t ws_size,
                              hipStream_t stream) {
    const float* emb  = (const float*)d_in[0];
    const float* bank = (const float*)d_in[1];
    const int Q      = in_sizes[0] / KD;             // 8192
    const int B      = Q / 1024;                     // 8
    const int Nbank  = in_sizes[1] / KD;             // 20000
    const int ntiles = (Nbank + NT - 1) / NT;        // 157
    const int Npad   = ntiles * NT;                  // 20096
    const int Mtiles = Q / MT;                       // 64

    // workspace layout
    unsigned char* qf8 = (unsigned char*)d_ws;                         // Q*KD bytes
    unsigned char* bf8 = qf8 + (size_t)Q * KD;                         // Npad*KD bytes
    float* fbase  = (float*)(bf8 + (size_t)Npad * KD);
    float* q2     = fbase;                                             // Q
    float* b2     = q2 + Q;                                            // Npad
    float* cand   = b2 + Npad;                                         // 16*Q*3
    float* scores = cand + (size_t)16 * Q * 3;                         // Q
    float* out    = (float*)d_out;

    hipLaunchKernelGGL(q_prep_k, dim3(B * 16), dim3(256), 0, stream, emb, qf8, q2);
    hipLaunchKernelGGL(bank_prep_k, dim3((Npad * 64 + 255) / 256), dim3(256), 0, stream,
                       bank, bf8, b2, Nbank, Npad);
    hipLaunchKernelGGL(knn_mfma_k, dim3(Mtiles * NSP), dim3(512), 0, stream,
                       qf8, bf8, b2, cand, ntiles, Q);
    hipLaunchKernelGGL(scores_k, dim3((Q + 255) / 256), dim3(256), 0, stream,
                       cand, q2, scores, Q);
    hipLaunchKernelGGL(upsample_k, dim3((out_size + 255) / 256), dim3(256), 0, stream,
                       scores, out, out_size);
}

// Round 8
// 401.511 us; speedup vs baseline: 2.5103x; 2.5103x over previous
//
#include <hip/hip_runtime.h>
#include <math.h>

#define KD     768     // embedding dim (elements = bytes in fp8)
#define MT     128     // M tile (queries) per block
#define NT     128     // N tile (bank rows)
#define KB     128     // K bytes per chunk (one mfma_scale K=128)
#define NKC    6       // K chunks (768/128)
#define NSPLIT 32      // bank splits per M tile
#define BIGF   3.0e38f

typedef __attribute__((ext_vector_type(4))) int   i32x4;
typedef __attribute__((ext_vector_type(8))) int   i32x8;
typedef __attribute__((ext_vector_type(4))) float f32x4;

// ---- software RNE float -> OCP e4m3fn (data ~N(0,1); saturation irrelevant)
__device__ __forceinline__ unsigned f2e4m3(float x) {
    unsigned u = __float_as_uint(x);
    unsigned s = (u >> 24) & 0x80u;
    float ax = __uint_as_float(u & 0x7fffffffu);
    if (ax < 0.015625f) {                       // subnormal region: step 2^-9
        int n = (int)rintf(ax * 512.0f);        // RNE, n in [0,8]
        if (n >= 8) return s | 0x08u;
        return s | (unsigned)n;
    }
    if (ax >= 464.0f) return s | 0x7Eu;         // saturate to 448
    unsigned m = __float_as_uint(ax);
    unsigned low = m & 0xFFFFFu;
    unsigned r = m >> 20;
    r += (low > 0x80000u) || (low == 0x80000u && (r & 1u));
    int ef = (int)(r >> 3) - 120;               // -127 + 7 (carry-safe)
    return s | ((unsigned)ef << 3) | (r & 7u);
}

__device__ __forceinline__ void ins3(float* t, float v) {
    float lo0 = fminf(t[0], v);
    float hi0 = fmaxf(t[0], v);
    float lo1 = fminf(t[1], hi0);
    float hi1 = fmaxf(t[1], hi0);
    float lo2 = fminf(t[2], hi1);
    t[0] = lo0; t[1] = lo1; t[2] = lo2;
}
__device__ __forceinline__ void async16(unsigned char* lds, const unsigned char* g) {
    __builtin_amdgcn_global_load_lds(
        (const __attribute__((address_space(1))) unsigned int*)g,
        (__attribute__((address_space(3))) unsigned int*)lds, 16, 0, 0);
}

// ---- emb [B][768][1024] -> qf8 [B*1024][768] e4m3 + exact fp32 q2 (fused) ----
__global__ void q_prep_k(const float* __restrict__ emb, unsigned char* __restrict__ qf8,
                         float* __restrict__ q2) {
    __shared__ float s[64][65];
    int b   = blockIdx.x >> 4;
    int hw0 = (blockIdx.x & 15) * 64;
    const float* src = emb + (size_t)b * KD * 1024;
    unsigned int* q4 = (unsigned int*)qf8;
    float part[4] = {0.f, 0.f, 0.f, 0.f};
    for (int e0 = 0; e0 < KD; e0 += 64) {
        __syncthreads();
        #pragma unroll
        for (int i = 0; i < 16; ++i) {
            int idx = threadIdx.x + i * 256;      // 0..4095
            int ee = idx >> 6, hh = idx & 63;
            s[ee][hh] = src[(size_t)(e0 + ee) * 1024 + hw0 + hh];
        }
        __syncthreads();
        #pragma unroll
        for (int i = 0; i < 4; ++i) {
            int slot = threadIdx.x + i * 256;     // 0..1023 : (qq, e4)
            int qq = slot >> 4, e4 = slot & 15;
            float v0 = s[e4 * 4 + 0][qq], v1 = s[e4 * 4 + 1][qq];
            float v2 = s[e4 * 4 + 2][qq], v3 = s[e4 * 4 + 3][qq];
            unsigned p = f2e4m3(v0) | (f2e4m3(v1) << 8)
                       | (f2e4m3(v2) << 16) | (f2e4m3(v3) << 24);
            q4[((size_t)b * 1024 + hw0 + qq) * (KD / 4) + e0 / 4 + e4] = p;
            part[i] = fmaf(v0, v0, part[i]); part[i] = fmaf(v1, v1, part[i]);
            part[i] = fmaf(v2, v2, part[i]); part[i] = fmaf(v3, v3, part[i]);
        }
    }
    #pragma unroll
    for (int i = 0; i < 4; ++i) {                 // 16 consecutive lanes share qq
        float p = part[i];
        #pragma unroll
        for (int off = 1; off < 16; off <<= 1) p += __shfl_xor(p, off, 64);
        if ((threadIdx.x & 15) == 0) {
            int qq = (threadIdx.x + i * 256) >> 4;
            q2[b * 1024 + hw0 + qq] = p;
        }
    }
}

// ---- bank -> bf8 e4m3 (zero-padded) + exact fp32 b2 norms (BIGF pad) ----
__global__ void bank_prep_k(const float* __restrict__ bank, unsigned char* __restrict__ bf8,
                            float* __restrict__ b2, int N, int Npad) {
    int gid = blockIdx.x * 256 + threadIdx.x;
    int row = gid >> 6, lane = gid & 63;
    if (row >= Npad) return;
    unsigned int* b4 = (unsigned int*)bf8;
    if (row < N) {
        const float4* src = (const float4*)(bank + (size_t)row * KD);
        float s = 0.f;
        #pragma unroll
        for (int i = 0; i < KD / 256; ++i) {
            float4 v = src[lane + i * 64];
            s = fmaf(v.x, v.x, s); s = fmaf(v.y, v.y, s);
            s = fmaf(v.z, v.z, s); s = fmaf(v.w, v.w, s);
            unsigned p = f2e4m3(v.x) | (f2e4m3(v.y) << 8)
                       | (f2e4m3(v.z) << 16) | (f2e4m3(v.w) << 24);
            b4[(size_t)row * (KD / 4) + lane + i * 64] = p;
        }
        #pragma unroll
        for (int off = 32; off; off >>= 1) s += __shfl_down(s, off, 64);
        if (lane == 0) b2[row] = s;
    } else {
        #pragma unroll
        for (int i = 0; i < KD / 256; ++i) b4[(size_t)row * (KD / 4) + lane + i * 64] = 0;
        if (lane == 0) b2[row] = BIGF;
    }
}

// ---- stage one 32 KB chunk (A 16 KB + B 16 KB), XOR-swizzled, 512 threads ----
__device__ __forceinline__ void stage_chunk(unsigned char (*stage)[MT * KB],
                                            const unsigned char* gA, const unsigned char* gB,
                                            int k0, int tid) {
    #pragma unroll
    for (int i = 0; i < 2; ++i) {
        int s = tid + i * 512;
        int m = s >> 3, g = s & 7;
        int G = g ^ (m & 7);
        async16(&stage[0][s * 16], gA + (size_t)m * KD + k0 + G * 16);
    }
    #pragma unroll
    for (int i = 0; i < 2; ++i) {
        int s = tid + i * 512;
        int m = s >> 3, g = s & 7;
        int G = g ^ (m & 7);
        async16(&stage[1][s * 16], gB + (size_t)m * KD + k0 + G * 16);
    }
}

__device__ __forceinline__ i32x8 frag_read(const unsigned char* st, int base, int o0, int o1) {
    i32x4 lo = *(const i32x4*)&st[base + o0];
    i32x4 hi = *(const i32x4*)&st[base + o1];
    return __builtin_shufflevector(lo, hi, 0, 1, 2, 3, 4, 5, 6, 7);
}

__device__ __forceinline__ void mfma_chunk(const unsigned char (*stage)[MT * KB],
                                           f32x4 acc[2][4], int wm, int wn,
                                           int l15, int quad, int xr) {
    const int o0 = ((2 * quad) ^ xr) * 16;
    const int o1 = ((2 * quad + 1) ^ xr) * 16;
    i32x8 af[2];
    #pragma unroll
    for (int mi = 0; mi < 2; ++mi)
        af[mi] = frag_read(stage[0], (32 * wm + 16 * mi + l15) * KB, o0, o1);
    #pragma unroll
    for (int ni = 0; ni < 4; ++ni) {
        i32x8 bfr = frag_read(stage[1], (64 * wn + 16 * ni + l15) * KB, o0, o1);
        #pragma unroll
        for (int mi = 0; mi < 2; ++mi)
            acc[mi][ni] = __builtin_amdgcn_mfma_scale_f32_16x16x128_f8f6f4(
                af[mi], bfr, acc[mi][ni], 0, 0,   // fp8 x fp8
                0, 127, 0, 127);                  // identity E8M0 scales
    }
}

// epilogue: s = b2 - 2*dot (q2 added in scores_k; per-row const preserves order)
__device__ __forceinline__ void do_epilogue(const f32x4 acc[2][4], const float b2v[4],
                                            float* top3) {
    #pragma unroll
    for (int ni = 0; ni < 4; ++ni)
        #pragma unroll
        for (int mi = 0; mi < 2; ++mi)
            #pragma unroll
            for (int r = 0; r < 4; ++r) {
                float s = fmaf(-2.0f, acc[mi][ni][r], b2v[ni]);
                ins3(&top3[(mi * 4 + r) * 3], s);
            }
}

// ---- main: fp8 MFMA distance GEMM + fused top-3, 512 thr, 2 blocks/CU ----
// grid = 2048 = 64 mt x 32 sp, in 4 temporal rounds of 512 resident blocks.
// Decode: per XCD per round = 16 FIXED mts x 4 sps -> L2 hot set = A 1.5 MB
// (resident across all rounds) + B 4 x 0.48 MB = 3.4 MB < 4 MB L2.
// 8 waves: wm=wid&3 (M quarter), wn=wid>>2 (N half) -> 8 rows/lane ->
// top3 = 24 regs + acc 32: fits 128-VGPR cap, NO scratch spill.
__global__ __launch_bounds__(512, 4)
void knn_mfma_k(const unsigned char* __restrict__ qf8, const unsigned char* __restrict__ bf8,
                const float* __restrict__ b2g, float* __restrict__ cand,
                int ntiles, int Q) {
    __shared__ unsigned char stage[2][MT * KB];   // A | B chunk (32768 B)

    const int tid  = threadIdx.x;
    const int lane = tid & 63;
    const int quad = lane >> 4;
    const int l15  = lane & 15;
    const int wid  = tid >> 6;                    // 0..7
    const int wm   = wid & 3;                     // M quarter (32 rows)
    const int wn   = wid >> 2;                    // N half (64 rows)
    const int xr   = l15 & 7;

    const int bx   = blockIdx.x;
    const int xcd  = bx & 7;
    const int rr_  = bx >> 9;                     // temporal round 0..3
    const int jj   = (bx >> 3) & 63;
    const int mt   = (xcd & 3) * 16 + (jj & 15);          // 0..63, fixed per XCD
    const int sp   = (jj >> 4) + 4 * (xcd >> 2) + 8 * rr_; // 0..31
    const int Mbase = mt * MT;

    float top3[24];
    #pragma unroll
    for (int i = 0; i < 24; ++i) top3[i] = BIGF;

    const unsigned char* gA = qf8 + (size_t)Mbase * KD;

    f32x4 acc[2][4];
    float b2v[4];
    bool first = true;

    for (int nt = sp; nt < ntiles; nt += NSPLIT) {
        const size_t nbase = (size_t)nt * NT;
        const unsigned char* gB = bf8 + nbase * KD;

        __syncthreads();                          // prior chunk reads complete
        stage_chunk(stage, gA, gB, 0, tid);       // kc0 staging in flight
        float t0 = b2g[nbase + 64 * wn + 0  + l15];
        float t1 = b2g[nbase + 64 * wn + 16 + l15];
        float t2 = b2g[nbase + 64 * wn + 32 + l15];
        float t3 = b2g[nbase + 64 * wn + 48 + l15];
        if (!first) do_epilogue(acc, b2v, top3);  // overlaps staging latency
        first = false;
        b2v[0] = t0; b2v[1] = t1; b2v[2] = t2; b2v[3] = t3;
        #pragma unroll
        for (int a = 0; a < 2; ++a)
            #pragma unroll
            for (int b = 0; b < 4; ++b) acc[a][b] = (f32x4){0.f, 0.f, 0.f, 0.f};
        __syncthreads();                          // kc0 loads complete
        mfma_chunk(stage, acc, wm, wn, l15, quad, xr);

        for (int kc = 1; kc < NKC; ++kc) {
            __syncthreads();
            stage_chunk(stage, gA, gB, kc * KB, tid);
            __syncthreads();
            mfma_chunk(stage, acc, wm, wn, l15, quad, xr);
        }
    }
    do_epilogue(acc, b2v, top3);

    // merge the 16 column-partials per query row via shfl_xor butterfly
    #pragma unroll
    for (int mi = 0; mi < 2; ++mi)
        #pragma unroll
        for (int r = 0; r < 4; ++r) {
            float a0 = top3[(mi * 4 + r) * 3 + 0];
            float a1 = top3[(mi * 4 + r) * 3 + 1];
            float a2 = top3[(mi * 4 + r) * 3 + 2];
            #pragma unroll
            for (int off = 1; off < 16; off <<= 1) {
                float b0 = __shfl_xor(a0, off, 64);
                float b1 = __shfl_xor(a1, off, 64);
                float b2x = __shfl_xor(a2, off, 64);
                float t[3] = {a0, a1, a2};
                ins3(t, b0); ins3(t, b1); ins3(t, b2x);
                a0 = t[0]; a1 = t[1]; a2 = t[2];
            }
            if (l15 == 0) {
                int row = Mbase + 32 * wm + 16 * mi + 4 * quad + r;
                float* o = cand + ((size_t)(sp * 2 + wn) * Q + row) * 3;
                o[0] = a0; o[1] = a1; o[2] = a2;
            }
        }
}

// ---- merge 64 split-partials (s = b2-2dot) -> d2 = q2+s -> mean sqrt ----
__global__ void scores_k(const float* __restrict__ cand, const float* __restrict__ q2g,
                         float* __restrict__ scores, int Q) {
    int idx = blockIdx.x * blockDim.x + threadIdx.x;
    if (idx >= Q) return;
    float best[3] = {BIGF, BIGF, BIGF};
    for (int sp = 0; sp < NSPLIT * 2; sp++) {
        const float* c = cand + ((size_t)sp * Q + idx) * 3;
        ins3(best, c[0]); ins3(best, c[1]); ins3(best, c[2]);
    }
    float q2 = q2g[idx];
    float s = (sqrtf(fmaxf(q2 + best[0], 1e-12f)) +
               sqrtf(fmaxf(q2 + best[1], 1e-12f)) +
               sqrtf(fmaxf(q2 + best[2], 1e-12f))) * (1.f / 3.f);
    scores[idx] = s;
}

// ---- bilinear x16 upsample, half-pixel, edge clamp ----
__global__ void upsample_k(const float* __restrict__ scores, float* __restrict__ out, int total) {
    int idx = blockIdx.x * blockDim.x + threadIdx.x;
    if (idx >= total) return;
    int x = idx & 511;
    int y = (idx >> 9) & 511;
    int b = idx >> 18;
    float sx = (x + 0.5f) * (1.f / 16.f) - 0.5f;
    float sy = (y + 0.5f) * (1.f / 16.f) - 0.5f;
    int x0 = (int)floorf(sx);
    int y0 = (int)floorf(sy);
    float wx = sx - (float)x0;
    float wy = sy - (float)y0;
    int x0c = min(max(x0, 0), 31), x1c = min(max(x0 + 1, 0), 31);
    int y0c = min(max(y0, 0), 31), y1c = min(max(y0 + 1, 0), 31);
    const float* sb = scores + (size_t)b * 1024;
    float v00 = sb[y0c * 32 + x0c], v01 = sb[y0c * 32 + x1c];
    float v10 = sb[y1c * 32 + x0c], v11 = sb[y1c * 32 + x1c];
    float v0 = v00 + wx * (v01 - v00);
    float v1 = v10 + wx * (v11 - v10);
    out[idx] = v0 + wy * (v1 - v0);
}

extern "C" void kernel_launch(void* const* d_in, const int* in_sizes, int n_in,
                              void* d_out, int out_size, void* d_ws, size_t ws_size,
                              hipStream_t stream) {
    const float* emb  = (const float*)d_in[0];
    const float* bank = (const float*)d_in[1];
    const int Q      = in_sizes[0] / KD;             // 8192
    const int B      = Q / 1024;                     // 8
    const int Nbank  = in_sizes[1] / KD;             // 20000
    const int ntiles = (Nbank + NT - 1) / NT;        // 157
    const int Npad   = ntiles * NT;                  // 20096
    const int Mtiles = Q / MT;                       // 64

    // workspace layout
    unsigned char* qf8 = (unsigned char*)d_ws;                         // Q*KD bytes
    unsigned char* bf8 = qf8 + (size_t)Q * KD;                         // Npad*KD bytes
    float* fbase  = (float*)(bf8 + (size_t)Npad * KD);
    float* q2     = fbase;                                             // Q
    float* b2     = q2 + Q;                                            // Npad
    float* cand   = b2 + Npad;                                         // NSPLIT*2*Q*3
    float* scores = cand + (size_t)NSPLIT * 2 * Q * 3;                 // Q
    float* out    = (float*)d_out;

    hipLaunchKernelGGL(q_prep_k, dim3(B * 16), dim3(256), 0, stream, emb, qf8, q2);
    hipLaunchKernelGGL(bank_prep_k, dim3((Npad * 64 + 255) / 256), dim3(256), 0, stream,
                       bank, bf8, b2, Nbank, Npad);
    hipLaunchKernelGGL(knn_mfma_k, dim3(Mtiles * NSPLIT), dim3(512), 0, stream,
                       qf8, bf8, b2, cand, ntiles, Q);
    hipLaunchKernelGGL(scores_k, dim3((Q + 255) / 256), dim3(256), 0, stream,
                       cand, q2, scores, Q);
    hipLaunchKernelGGL(upsample_k, dim3((out_size + 255) / 256), dim3(256), 0, stream,
                       scores, out, out_size);
}

// Round 9
// 376.843 us; speedup vs baseline: 2.6746x; 1.0655x over previous
//
#include <hip/hip_runtime.h>
#include <math.h>

#define KD     768     // embedding dim (elements = bytes in fp8)
#define MT     128     // M tile (queries) per block
#define NT     128     // N tile (bank rows)
#define KB     128     // K bytes per mfma_scale (K=128)
#define NKC    6       // K chunks per tile (768/128)
#define NSPLIT 32      // bank splits per M tile
#define BIGF   3.0e38f

typedef __attribute__((ext_vector_type(4))) int   i32x4;
typedef __attribute__((ext_vector_type(8))) int   i32x8;
typedef __attribute__((ext_vector_type(4))) float f32x4;

// ---- software RNE float -> OCP e4m3fn (data ~N(0,1); saturation irrelevant)
__device__ __forceinline__ unsigned f2e4m3(float x) {
    unsigned u = __float_as_uint(x);
    unsigned s = (u >> 24) & 0x80u;
    float ax = __uint_as_float(u & 0x7fffffffu);
    if (ax < 0.015625f) {                       // subnormal region: step 2^-9
        int n = (int)rintf(ax * 512.0f);        // RNE, n in [0,8]
        if (n >= 8) return s | 0x08u;
        return s | (unsigned)n;
    }
    if (ax >= 464.0f) return s | 0x7Eu;         // saturate to 448
    unsigned m = __float_as_uint(ax);
    unsigned low = m & 0xFFFFFu;
    unsigned r = m >> 20;
    r += (low > 0x80000u) || (low == 0x80000u && (r & 1u));
    int ef = (int)(r >> 3) - 120;               // -127 + 7 (carry-safe)
    return s | ((unsigned)ef << 3) | (r & 7u);
}

__device__ __forceinline__ void ins3(float* t, float v) {
    float lo0 = fminf(t[0], v);
    float hi0 = fmaxf(t[0], v);
    float lo1 = fminf(t[1], hi0);
    float hi1 = fmaxf(t[1], hi0);
    float lo2 = fminf(t[2], hi1);
    t[0] = lo0; t[1] = lo1; t[2] = lo2;
}
__device__ __forceinline__ void async16(unsigned char* lds, const unsigned char* g) {
    __builtin_amdgcn_global_load_lds(
        (const __attribute__((address_space(1))) unsigned int*)g,
        (__attribute__((address_space(3))) unsigned int*)lds, 16, 0, 0);
}

// ---- emb [B][768][1024] -> qf8 [B*1024][768] e4m3 + q2 partials (atomicAdd) ----
// grid = B * 16 hw-tiles * 3 e-groups (256 e each)
__global__ void q_prep_k(const float* __restrict__ emb, unsigned char* __restrict__ qf8,
                         float* __restrict__ q2) {
    __shared__ float s[64][65];
    int bx  = blockIdx.x;
    int b   = bx / 48;
    int rem = bx % 48;
    int hw0 = (rem & 15) * 64;
    int eg  = rem >> 4;                           // 0..2
    const float* src = emb + (size_t)b * KD * 1024;
    unsigned int* q4 = (unsigned int*)qf8;
    float part[4] = {0.f, 0.f, 0.f, 0.f};
    for (int e0 = eg * 256; e0 < eg * 256 + 256; e0 += 64) {
        __syncthreads();
        #pragma unroll
        for (int i = 0; i < 16; ++i) {
            int idx = threadIdx.x + i * 256;      // 0..4095
            int ee = idx >> 6, hh = idx & 63;
            s[ee][hh] = src[(size_t)(e0 + ee) * 1024 + hw0 + hh];
        }
        __syncthreads();
        #pragma unroll
        for (int i = 0; i < 4; ++i) {
            int slot = threadIdx.x + i * 256;     // 0..1023 : (qq, e4)
            int qq = slot >> 4, e4 = slot & 15;
            float v0 = s[e4 * 4 + 0][qq], v1 = s[e4 * 4 + 1][qq];
            float v2 = s[e4 * 4 + 2][qq], v3 = s[e4 * 4 + 3][qq];
            unsigned p = f2e4m3(v0) | (f2e4m3(v1) << 8)
                       | (f2e4m3(v2) << 16) | (f2e4m3(v3) << 24);
            q4[((size_t)b * 1024 + hw0 + qq) * (KD / 4) + e0 / 4 + e4] = p;
            part[i] = fmaf(v0, v0, part[i]); part[i] = fmaf(v1, v1, part[i]);
            part[i] = fmaf(v2, v2, part[i]); part[i] = fmaf(v3, v3, part[i]);
        }
    }
    #pragma unroll
    for (int i = 0; i < 4; ++i) {                 // 16 consecutive lanes share qq
        float p = part[i];
        #pragma unroll
        for (int off = 1; off < 16; off <<= 1) p += __shfl_xor(p, off, 64);
        if ((threadIdx.x & 15) == 0) {
            int qq = (threadIdx.x + i * 256) >> 4;
            atomicAdd(&q2[b * 1024 + hw0 + qq], p);
        }
    }
}

// ---- bank -> bf8 e4m3 (zero-padded) + exact fp32 b2 norms (BIGF pad) ----
__global__ void bank_prep_k(const float* __restrict__ bank, unsigned char* __restrict__ bf8,
                            float* __restrict__ b2, int N, int Npad) {
    int gid = blockIdx.x * 256 + threadIdx.x;
    int row = gid >> 6, lane = gid & 63;
    if (row >= Npad) return;
    unsigned int* b4 = (unsigned int*)bf8;
    if (row < N) {
        const float4* src = (const float4*)(bank + (size_t)row * KD);
        float s = 0.f;
        #pragma unroll
        for (int i = 0; i < KD / 256; ++i) {
            float4 v = src[lane + i * 64];
            s = fmaf(v.x, v.x, s); s = fmaf(v.y, v.y, s);
            s = fmaf(v.z, v.z, s); s = fmaf(v.w, v.w, s);
            unsigned p = f2e4m3(v.x) | (f2e4m3(v.y) << 8)
                       | (f2e4m3(v.z) << 16) | (f2e4m3(v.w) << 24);
            b4[(size_t)row * (KD / 4) + lane + i * 64] = p;
        }
        #pragma unroll
        for (int off = 32; off; off >>= 1) s += __shfl_down(s, off, 64);
        if (lane == 0) b2[row] = s;
    } else {
        #pragma unroll
        for (int i = 0; i < KD / 256; ++i) b4[(size_t)row * (KD / 4) + lane + i * 64] = 0;
        if (lane == 0) b2[row] = BIGF;
    }
}

// ---- stage a 64 KB double-chunk: A(kc),B(kc),A(kc+1),B(kc+1), XOR-swizzled ----
__device__ __forceinline__ void stage_pair(unsigned char (*stage)[MT * KB],
                                           const unsigned char* gA, const unsigned char* gB,
                                           int k0, int tid) {
    #pragma unroll
    for (int h = 0; h < 2; ++h) {                 // chunk k0, k0+KB
        #pragma unroll
        for (int i = 0; i < 2; ++i) {
            int s = tid + i * 512;
            int m = s >> 3, g = s & 7;
            int G = g ^ (m & 7);
            async16(&stage[2 * h + 0][s * 16], gA + (size_t)m * KD + k0 + h * KB + G * 16);
        }
        #pragma unroll
        for (int i = 0; i < 2; ++i) {
            int s = tid + i * 512;
            int m = s >> 3, g = s & 7;
            int G = g ^ (m & 7);
            async16(&stage[2 * h + 1][s * 16], gB + (size_t)m * KD + k0 + h * KB + G * 16);
        }
    }
}

__device__ __forceinline__ i32x8 frag_read(const unsigned char* st, int base, int o0, int o1) {
    i32x4 lo = *(const i32x4*)&st[base + o0];
    i32x4 hi = *(const i32x4*)&st[base + o1];
    return __builtin_shufflevector(lo, hi, 0, 1, 2, 3, 4, 5, 6, 7);
}

__device__ __forceinline__ void mfma_chunk(const unsigned char* stA, const unsigned char* stB,
                                           f32x4 acc[2][4], int wm, int wn,
                                           int l15, int quad, int xr) {
    const int o0 = ((2 * quad) ^ xr) * 16;
    const int o1 = ((2 * quad + 1) ^ xr) * 16;
    i32x8 af[2];
    #pragma unroll
    for (int mi = 0; mi < 2; ++mi)
        af[mi] = frag_read(stA, (32 * wm + 16 * mi + l15) * KB, o0, o1);
    #pragma unroll
    for (int ni = 0; ni < 4; ++ni) {
        i32x8 bfr = frag_read(stB, (64 * wn + 16 * ni + l15) * KB, o0, o1);
        #pragma unroll
        for (int mi = 0; mi < 2; ++mi)
            acc[mi][ni] = __builtin_amdgcn_mfma_scale_f32_16x16x128_f8f6f4(
                af[mi], bfr, acc[mi][ni], 0, 0,   // fp8 x fp8
                0, 127, 0, 127);                  // identity E8M0 scales
    }
}

// epilogue: s = b2 - 2*dot (q2 added in scores_k; per-row const preserves order)
__device__ __forceinline__ void do_epilogue(const f32x4 acc[2][4], const float b2v[4],
                                            float* top3) {
    #pragma unroll
    for (int ni = 0; ni < 4; ++ni)
        #pragma unroll
        for (int mi = 0; mi < 2; ++mi)
            #pragma unroll
            for (int r = 0; r < 4; ++r) {
                float s = fmaf(-2.0f, acc[mi][ni][r], b2v[ni]);
                ins3(&top3[(mi * 4 + r) * 3], s);
            }
}

// ---- main: fp8 MFMA distance GEMM + fused top-3, 512 thr, 2 blocks/CU ----
// grid = 2048 = 64 mt x 32 sp, 4 temporal rounds of 512 resident blocks.
// Per XCD per round: 16 FIXED mts x 4 sps -> L2 hot set = A 1.5 MB + B ~1.9 MB.
// BK=256: stage 2 K-chunks (64 KB) per barrier pair -> half the barriers of R8,
// 16 MFMA/wave per pair. LDS 64 KB/block x 2 blocks = 128 KB/CU (occupancy kept).
__global__ __launch_bounds__(512, 4)
void knn_mfma_k(const unsigned char* __restrict__ qf8, const unsigned char* __restrict__ bf8,
                const float* __restrict__ b2g, float* __restrict__ cand,
                int ntiles, int Q) {
    __shared__ unsigned char stage[4][MT * KB];   // A0|B0|A1|B1 (65536 B)

    const int tid  = threadIdx.x;
    const int lane = tid & 63;
    const int quad = lane >> 4;
    const int l15  = lane & 15;
    const int wid  = tid >> 6;                    // 0..7
    const int wm   = wid & 3;                     // M quarter (32 rows)
    const int wn   = wid >> 2;                    // N half (64 rows)
    const int xr   = l15 & 7;

    const int bx   = blockIdx.x;
    const int xcd  = bx & 7;
    const int rr_  = bx >> 9;                     // temporal round 0..3
    const int jj   = (bx >> 3) & 63;
    const int mt   = (xcd & 3) * 16 + (jj & 15);           // fixed per XCD
    const int sp   = (jj >> 4) + 4 * (xcd >> 2) + 8 * rr_; // 0..31
    const int Mbase = mt * MT;

    float top3[24];
    #pragma unroll
    for (int i = 0; i < 24; ++i) top3[i] = BIGF;

    const unsigned char* gA = qf8 + (size_t)Mbase * KD;

    f32x4 acc[2][4];
    float b2v[4];
    bool first = true;

    for (int nt = sp; nt < ntiles; nt += NSPLIT) {
        const size_t nbase = (size_t)nt * NT;
        const unsigned char* gB = bf8 + nbase * KD;

        __syncthreads();                          // prior pair reads complete
        stage_pair(stage, gA, gB, 0, tid);        // chunks 0,1 in flight
        float t0 = b2g[nbase + 64 * wn + 0  + l15];
        float t1 = b2g[nbase + 64 * wn + 16 + l15];
        float t2 = b2g[nbase + 64 * wn + 32 + l15];
        float t3 = b2g[nbase + 64 * wn + 48 + l15];
        if (!first) do_epilogue(acc, b2v, top3);  // overlaps staging latency
        first = false;
        b2v[0] = t0; b2v[1] = t1; b2v[2] = t2; b2v[3] = t3;
        #pragma unroll
        for (int a = 0; a < 2; ++a)
            #pragma unroll
            for (int b = 0; b < 4; ++b) acc[a][b] = (f32x4){0.f, 0.f, 0.f, 0.f};
        __syncthreads();                          // chunks 0,1 resident
        mfma_chunk(stage[0], stage[1], acc, wm, wn, l15, quad, xr);
        mfma_chunk(stage[2], stage[3], acc, wm, wn, l15, quad, xr);

        #pragma unroll
        for (int p = 1; p < NKC / 2; ++p) {
            __syncthreads();
            stage_pair(stage, gA, gB, 2 * p * KB, tid);
            __syncthreads();
            mfma_chunk(stage[0], stage[1], acc, wm, wn, l15, quad, xr);
            mfma_chunk(stage[2], stage[3], acc, wm, wn, l15, quad, xr);
        }
    }
    do_epilogue(acc, b2v, top3);

    // merge the 16 column-partials per query row via shfl_xor butterfly
    #pragma unroll
    for (int mi = 0; mi < 2; ++mi)
        #pragma unroll
        for (int r = 0; r < 4; ++r) {
            float a0 = top3[(mi * 4 + r) * 3 + 0];
            float a1 = top3[(mi * 4 + r) * 3 + 1];
            float a2 = top3[(mi * 4 + r) * 3 + 2];
            #pragma unroll
            for (int off = 1; off < 16; off <<= 1) {
                float b0 = __shfl_xor(a0, off, 64);
                float b1 = __shfl_xor(a1, off, 64);
                float b2x = __shfl_xor(a2, off, 64);
                float t[3] = {a0, a1, a2};
                ins3(t, b0); ins3(t, b1); ins3(t, b2x);
                a0 = t[0]; a1 = t[1]; a2 = t[2];
            }
            if (l15 == 0) {
                int row = Mbase + 32 * wm + 16 * mi + 4 * quad + r;
                float* o = cand + ((size_t)(sp * 2 + wn) * Q + row) * 3;
                o[0] = a0; o[1] = a1; o[2] = a2;
            }
        }
}

// ---- merge 64 split-partials: one WAVE per query, lane = partial ----
__global__ void scores_k(const float* __restrict__ cand, const float* __restrict__ q2g,
                         float* __restrict__ scores, int Q) {
    int gid  = blockIdx.x * 256 + threadIdx.x;
    int q    = gid >> 6;
    int lane = gid & 63;
    if (q >= Q) return;
    const float* c = cand + ((size_t)lane * Q + q) * 3;
    float a0 = c[0], a1 = c[1], a2 = c[2];
    #pragma unroll
    for (int off = 1; off < 64; off <<= 1) {
        float b0 = __shfl_xor(a0, off, 64);
        float b1 = __shfl_xor(a1, off, 64);
        float b2x = __shfl_xor(a2, off, 64);
        float t[3] = {a0, a1, a2};
        ins3(t, b0); ins3(t, b1); ins3(t, b2x);
        a0 = t[0]; a1 = t[1]; a2 = t[2];
    }
    if (lane == 0) {
        float q2 = q2g[q];
        float s = (sqrtf(fmaxf(q2 + a0, 1e-12f)) +
                   sqrtf(fmaxf(q2 + a1, 1e-12f)) +
                   sqrtf(fmaxf(q2 + a2, 1e-12f))) * (1.f / 3.f);
        scores[q] = s;
    }
}

// ---- bilinear x16 upsample, half-pixel, edge clamp ----
__global__ void upsample_k(const float* __restrict__ scores, float* __restrict__ out, int total) {
    int idx = blockIdx.x * blockDim.x + threadIdx.x;
    if (idx >= total) return;
    int x = idx & 511;
    int y = (idx >> 9) & 511;
    int b = idx >> 18;
    float sx = (x + 0.5f) * (1.f / 16.f) - 0.5f;
    float sy = (y + 0.5f) * (1.f / 16.f) - 0.5f;
    int x0 = (int)floorf(sx);
    int y0 = (int)floorf(sy);
    float wx = sx - (float)x0;
    float wy = sy - (float)y0;
    int x0c = min(max(x0, 0), 31), x1c = min(max(x0 + 1, 0), 31);
    int y0c = min(max(y0, 0), 31), y1c = min(max(y0 + 1, 0), 31);
    const float* sb = scores + (size_t)b * 1024;
    float v00 = sb[y0c * 32 + x0c], v01 = sb[y0c * 32 + x1c];
    float v10 = sb[y1c * 32 + x0c], v11 = sb[y1c * 32 + x1c];
    float v0 = v00 + wx * (v01 - v00);
    float v1 = v10 + wx * (v11 - v10);
    out[idx] = v0 + wy * (v1 - v0);
}

extern "C" void kernel_launch(void* const* d_in, const int* in_sizes, int n_in,
                              void* d_out, int out_size, void* d_ws, size_t ws_size,
                              hipStream_t stream) {
    const float* emb  = (const float*)d_in[0];
    const float* bank = (const float*)d_in[1];
    const int Q      = in_sizes[0] / KD;             // 8192
    const int B      = Q / 1024;                     // 8
    const int Nbank  = in_sizes[1] / KD;             // 20000
    const int ntiles = (Nbank + NT - 1) / NT;        // 157
    const int Npad   = ntiles * NT;                  // 20096
    const int Mtiles = Q / MT;                       // 64

    // workspace layout
    unsigned char* qf8 = (unsigned char*)d_ws;                         // Q*KD bytes
    unsigned char* bf8 = qf8 + (size_t)Q * KD;                         // Npad*KD bytes
    float* fbase  = (float*)(bf8 + (size_t)Npad * KD);
    float* q2     = fbase;                                             // Q
    float* b2     = q2 + Q;                                            // Npad
    float* cand   = b2 + Npad;                                         // NSPLIT*2*Q*3
    float* scores = cand + (size_t)NSPLIT * 2 * Q * 3;                 // Q
    float* out    = (float*)d_out;

    hipMemsetAsync(q2, 0, Q * sizeof(float), stream);  // q2 accumulated via atomicAdd
    hipLaunchKernelGGL(q_prep_k, dim3(B * 48), dim3(256), 0, stream, emb, qf8, q2);
    hipLaunchKernelGGL(bank_prep_k, dim3((Npad * 64 + 255) / 256), dim3(256), 0, stream,
                       bank, bf8, b2, Nbank, Npad);
    hipLaunchKernelGGL(knn_mfma_k, dim3(Mtiles * NSPLIT), dim3(512), 0, stream,
                       qf8, bf8, b2, cand, ntiles, Q);
    hipLaunchKernelGGL(scores_k, dim3((Q * 64 + 255) / 256), dim3(256), 0, stream,
                       cand, q2, scores, Q);
    hipLaunchKernelGGL(upsample_k, dim3((out_size + 255) / 256), dim3(256), 0, stream,
                       scores, out, out_size);
}